// Round 3
// baseline (893.460 us; speedup 1.0000x reference)
//
#include <hip/hip_runtime.h>
#include <stdint.h>

typedef __attribute__((ext_vector_type(8))) short short8;
typedef __attribute__((ext_vector_type(4))) float floatx4;

#define SEQ    2048
#define HID    4096
#define NHEAD  32
#define HDIMV  128
#define PROJN  12288

__device__ __forceinline__ unsigned short f2bf(float f) {
  union { float f; unsigned u; } v; v.f = f;
  unsigned r = (v.u + 0x7fffu + ((v.u >> 16) & 1u)) >> 16;
  return (unsigned short)r;
}

// -------------------- async 16B global->LDS --------------------
__device__ __forceinline__ void g2l16(const void* g, void* l) {
  __builtin_amdgcn_global_load_lds(
      (const __attribute__((address_space(1))) void*)g,
      (__attribute__((address_space(3))) void*)l, 16, 0, 0);
}

// ---------- pack fp32 [R x K] row-major -> bf16 tile images ----------
// Tile (rp, kt) = 128 rows x 64 k, chunk-major: elem (r,c) at
// tile*8192 + ((c>>3)*128 + r)*8 + (c&7). Rows < scale_rows get multiplied by
// scale (used to fold the softmax 1/sqrt(d)*log2(e) into w_pack's Q rows).
__global__ __launch_bounds__(256) void pack_fp32(const float* __restrict__ src,
                                                 unsigned short* __restrict__ dst, int K,
                                                 int scale_rows, float scale) {
  const int rp = blockIdx.x, kt = blockIdx.y, t = threadIdx.x;
  const long tb = ((long)rp * gridDim.y + kt) * 8192;
#pragma unroll
  for (int j = 0; j < 4; j++) {
    int ch = t + j * 256;
    int r = ch & 127, cc = ch >> 7;
    float sc = (rp * 128 + r < scale_rows) ? scale : 1.0f;
    const float* s = src + (long)(rp * 128 + r) * K + kt * 64 + cc * 8;
    float4 a = *(const float4*)s;
    float4 b = *(const float4*)(s + 4);
    short8 o;
    o[0] = (short)f2bf(a.x * sc); o[1] = (short)f2bf(a.y * sc);
    o[2] = (short)f2bf(a.z * sc); o[3] = (short)f2bf(a.w * sc);
    o[4] = (short)f2bf(b.x * sc); o[5] = (short)f2bf(b.y * sc);
    o[6] = (short)f2bf(b.z * sc); o[7] = (short)f2bf(b.w * sc);
    *(short8*)(dst + tb + ch * 8) = o;
  }
}

// -------------------- double-buffered NT GEMM, BM=128 x BN=256, BK=64 ----------
// 8 waves (2M x 4N), 64x64 per wave. LDS: A 16KB x2 + B 32KB x2 = 96KB -> 1 blk/CU.
// Per K-step: issue 6 global_load_lds for kt+1 into other buffer, then
// s_waitcnt vmcnt(6) (waits ONLY the 6 oldest = current buffer; prefetch stays
// in flight), raw s_barrier, 32 MFMA under setprio(1), raw s_barrier.
// Packed chunk-major tiles -> conflict-free ds_read_b128, linear DMA dest.
// EPI 0: fp32 C row-major (gemm2).  EPI 1: fused QKV re-pack (gemm1).
template<int EPI>
__global__ __launch_bounds__(512, 2) void gemm_db(
    const unsigned short* __restrict__ Ap,
    const unsigned short* __restrict__ Bp,
    float* __restrict__ C, int N,
    unsigned short* __restrict__ Qf,
    unsigned short* __restrict__ Kf,
    unsigned short* __restrict__ Vf,
    int KT) {
  __shared__ __align__(16) unsigned short As[2][8192];
  __shared__ __align__(16) unsigned short Bs[2][16384];
  const int t = threadIdx.x;
  const int wave = t >> 6, lane = t & 63;
  const int bid = blockIdx.x;
  const int xcd = bid & 7;
  const int li = bid >> 3;
  const int mi = li & 15;
  const int npair = (li >> 4) * 8 + xcd;      // B pinned to XCD for L2 reuse
  const unsigned short* at  = Ap + (long)mi * KT * 8192 + t * 8;
  const unsigned short* bt0 = Bp + (long)(npair * 2) * KT * 8192 + t * 8;
  const unsigned short* bt1 = Bp + (long)(npair * 2 + 1) * KT * 8192 + t * 8;
  const int wr = wave >> 2, wc = wave & 3;
  const int mw = wr * 64;
  const int lq = lane & 15, lg = lane >> 4;

  floatx4 zero = {0.f, 0.f, 0.f, 0.f};
  floatx4 acc[4][4];
#pragma unroll
  for (int i = 0; i < 4; i++)
#pragma unroll
    for (int j = 0; j < 4; j++) acc[i][j] = zero;

  // stage K-tile kt into buffer buf: 6 x (512 thr x 16B) = 48KB, linear dest
  auto STAGE = [&](int buf, int kt) {
    const unsigned short* a  = at  + (long)kt * 8192;
    const unsigned short* b0 = bt0 + (long)kt * 8192;
    const unsigned short* b1 = bt1 + (long)kt * 8192;
    unsigned short* al = &As[buf][wave * 512];
    unsigned short* bl = &Bs[buf][wave * 512];
    g2l16(a, al);               g2l16(a + 4096, al + 4096);
    g2l16(b0, bl);              g2l16(b0 + 4096, bl + 4096);
    g2l16(b1, bl + 8192);       g2l16(b1 + 4096, bl + 12288);
  };

  STAGE(0, 0);
  for (int kt = 0; kt < KT; kt++) {
    const int cur = kt & 1;
    if (kt + 1 < KT) {
      STAGE(1 - cur, kt + 1);
      asm volatile("s_waitcnt vmcnt(6)" ::: "memory");  // cur buffer complete
    } else {
      asm volatile("s_waitcnt vmcnt(0)" ::: "memory");
    }
    __builtin_amdgcn_s_barrier();          // all waves' cur loads landed
    __builtin_amdgcn_sched_barrier(0);     // pin: no ds_read hoists above
    const unsigned short* ab = &As[cur][0];
    const unsigned short* bb = &Bs[cur][(wc >> 1) * 8192];
    const int nb = (wc & 1) * 64;
    __builtin_amdgcn_s_setprio(1);
#pragma unroll
    for (int kk = 0; kk < 2; kk++) {
      const int ch = (kk * 4 + lg) * 128;
      short8 af[4], bfr[4];
#pragma unroll
      for (int i = 0; i < 4; i++)
        af[i] = *(const short8*)(ab + (ch + mw + i * 16 + lq) * 8);
#pragma unroll
      for (int j = 0; j < 4; j++)
        bfr[j] = *(const short8*)(bb + (ch + nb + j * 16 + lq) * 8);
#pragma unroll
      for (int i = 0; i < 4; i++)
#pragma unroll
        for (int j = 0; j < 4; j++)
          acc[i][j] = __builtin_amdgcn_mfma_f32_16x16x32_bf16(af[i], bfr[j], acc[i][j], 0, 0, 0);
    }
    __builtin_amdgcn_s_setprio(0);
    __builtin_amdgcn_sched_barrier(0);
    __builtin_amdgcn_s_barrier();          // all waves done reading cur
  }

  if (EPI == 0) {
    const int row0 = mi * 128 + mw + lg * 4;
    const int col0 = npair * 256 + wc * 64 + lq;
#pragma unroll
    for (int i = 0; i < 4; i++)
#pragma unroll
      for (int j = 0; j < 4; j++)
#pragma unroll
        for (int r = 0; r < 4; r++)
          C[(long)(row0 + i * 16 + r) * N + col0 + j * 16] = acc[i][j][r];
  } else {
    // fused QKV re-pack: this wave's 64x64 tile lies in packed N-tile ni
    const int ni = npair * 2 + (wc >> 1);
    const int sec = ni >> 5;                // 0=Q, 1=K, 2=V
    const int h = ni & 31;
    unsigned short* dst =
        (sec == 0 ? Qf : (sec == 1 ? Kf : Vf)) + ((long)(h * 16 + mi)) * 16384;
    const int cb = (wc & 1) * 64;           // col base within the 128-col tile
    if (sec < 2) {
#pragma unroll
      for (int i = 0; i < 4; i++)
#pragma unroll
        for (int j = 0; j < 4; j++)
#pragma unroll
          for (int r = 0; r < 4; r++) {
            int row = mw + i * 16 + lg * 4 + r;   // local seq row
            int c = cb + j * 16 + lq;             // local head dim
            dst[((c >> 3) * 128 + row) * 8 + (c & 7)] = f2bf(acc[i][j][r]);
          }
    } else {
#pragma unroll
      for (int i = 0; i < 4; i++)
#pragma unroll
        for (int j = 0; j < 4; j++)
#pragma unroll
          for (int r = 0; r < 4; r++) {
            int s = mw + i * 16 + lg * 4 + r;     // seq row (becomes k)
            int d = cb + j * 16 + lq;             // head dim (becomes row)
            dst[((s >> 3) * 128 + d) * 8 + (s & 7)] = f2bf(acc[i][j][r]);
          }
    }
  }
}

// stage one contiguous 32KB packed tile into LDS (wave-cooperative, coalesced)
__device__ __forceinline__ void stage_tile(const unsigned short* g, unsigned short* lds,
                                           int wave, int lane) {
  const unsigned short* gp = g + wave * 4096 + lane * 8;
  unsigned short* lp = lds + wave * 4096;
#pragma unroll
  for (int j = 0; j < 8; j++) g2l16(gp + j * 512, lp + j * 512);
}

// -------------------- causal flash attention --------------------
// 512 blocks heavy-first: h = bx&31, qt = 15-(bx>>5). 4 waves, 32 q-rows each.
// K/V double-buffered in LDS (one barrier per kv iter, prefetch overlaps compute).
// Q frags in regs; P round-trip via wave-private 32KB LDS. Q pre-scaled (log2 dom).
__global__ __launch_bounds__(256, 1) void attn_kernel(
    const unsigned short* __restrict__ Qf,
    const unsigned short* __restrict__ Kf,
    const unsigned short* __restrict__ Vf,
    unsigned short* __restrict__ aop) {
  __shared__ __align__(16) unsigned short Ks[2][16384];
  __shared__ __align__(16) unsigned short Vs[2][16384];
  __shared__ __align__(16) unsigned short Ps[16384];
  const int bx = blockIdx.x;
  const int h = bx & 31;
  const int qt = 15 - (bx >> 5);
  const int t = threadIdx.x, wave = t >> 6, lane = t & 63;
  const int lq = lane & 15, lg = lane >> 4;
  const int wOff = wave * 32;

  // Q fragments: coalesced global reads from packed image (Q pre-scaled)
  const unsigned short* qb = Qf + ((long)(h * 16 + qt)) * 16384;
  short8 qf[2][4];
#pragma unroll
  for (int i = 0; i < 2; i++)
#pragma unroll
    for (int kk = 0; kk < 4; kk++)
      qf[i][kk] = *(const short8*)(qb + ((kk * 4 + lg) * 128 + wOff + i * 16 + lq) * 8);

  float mraw[2][4], lsum[2][4];
  floatx4 zero = {0.f, 0.f, 0.f, 0.f};
  floatx4 o[2][8];
#pragma unroll
  for (int i = 0; i < 2; i++)
#pragma unroll
    for (int r = 0; r < 4; r++) { mraw[i][r] = -INFINITY; lsum[i][r] = 0.f; }
#pragma unroll
  for (int i = 0; i < 2; i++)
#pragma unroll
    for (int j = 0; j < 8; j++) o[i][j] = zero;

  const unsigned short* kb0 = Kf + ((long)h * 16) * 16384;
  const unsigned short* vb0 = Vf + ((long)h * 16) * 16384;
  stage_tile(kb0, Ks[0], wave, lane);
  stage_tile(vb0, Vs[0], wave, lane);

  for (int kv = 0; kv <= qt; kv++) {
    const int cur = kv & 1;
    const bool diag = (kv == qt);
    __syncthreads();  // cur buffers staged; prev-iter LDS reads done
    if (!diag) {
      stage_tile(kb0 + (long)(kv + 1) * 16384, Ks[1 - cur], wave, lane);
      stage_tile(vb0 + (long)(kv + 1) * 16384, Vs[1 - cur], wave, lane);
    }

    // S = Q K^T (already in log2 domain via pre-scaled Q)
    floatx4 s[2][8];
#pragma unroll
    for (int i = 0; i < 2; i++)
#pragma unroll
      for (int j = 0; j < 8; j++) s[i][j] = zero;
#pragma unroll
    for (int kk = 0; kk < 4; kk++) {
      short8 bfr[8];
#pragma unroll
      for (int j = 0; j < 8; j++)
        bfr[j] = *(const short8*)(&Ks[cur][((kk * 4 + lg) * 128 + j * 16 + lq) * 8]);
#pragma unroll
      for (int i = 0; i < 2; i++)
#pragma unroll
        for (int j = 0; j < 8; j++)
          s[i][j] = __builtin_amdgcn_mfma_f32_16x16x32_bf16(qf[i][kk], bfr[j], s[i][j], 0, 0, 0);
    }

    if (diag) {
#pragma unroll
      for (int i = 0; i < 2; i++)
#pragma unroll
        for (int r = 0; r < 4; r++) {
          int qrow = qt * 128 + wOff + i * 16 + lg * 4 + r;
#pragma unroll
          for (int j = 0; j < 8; j++)
            if (kv * 128 + j * 16 + lq > qrow) s[i][j][r] = -INFINITY;
        }
    }

    // online softmax (log2 domain; rows lane-local, reduce over 16 col-lanes)
    float alpha_[2][4];
#pragma unroll
    for (int i = 0; i < 2; i++) {
#pragma unroll
      for (int r = 0; r < 4; r++) {
        float mx = s[i][0][r];
#pragma unroll
        for (int j = 1; j < 8; j++) mx = fmaxf(mx, s[i][j][r]);
#pragma unroll
        for (int d = 1; d < 16; d <<= 1) mx = fmaxf(mx, __shfl_xor(mx, d, 64));
        float mnew = fmaxf(mraw[i][r], mx);
        float al = exp2f(mraw[i][r] - mnew);
        float ps = 0.f;
#pragma unroll
        for (int j = 0; j < 8; j++) {
          float p = exp2f(s[i][j][r] - mnew);
          s[i][j][r] = p;
          ps += p;
        }
#pragma unroll
        for (int d = 1; d < 16; d <<= 1) ps += __shfl_xor(ps, d, 64);
        lsum[i][r] = lsum[i][r] * al + ps;
        mraw[i][r] = mnew;
        alpha_[i][r] = al;
      }
    }
#pragma unroll
    for (int i = 0; i < 2; i++)
#pragma unroll
      for (int j = 0; j < 8; j++)
#pragma unroll
        for (int r = 0; r < 4; r++) o[i][j][r] *= alpha_[i][r];

    // P (C-layout regs) -> chunk-major LDS, wave-private rows, no barrier
#pragma unroll
    for (int i = 0; i < 2; i++)
#pragma unroll
      for (int r = 0; r < 4; r++) {
        int prow = wOff + i * 16 + lg * 4 + r;
#pragma unroll
        for (int j = 0; j < 8; j++)
          Ps[((j * 2 + (lq >> 3)) * 128 + prow) * 8 + (lq & 7)] = f2bf(s[i][j][r]);
      }

    // O += P V (A-frags from own P rows, B-frags from Vs tile in LDS)
#pragma unroll
    for (int kk = 0; kk < 4; kk++) {
      short8 pf[2], vf[8];
#pragma unroll
      for (int i = 0; i < 2; i++)
        pf[i] = *(const short8*)(Ps + ((kk * 4 + lg) * 128 + wOff + i * 16 + lq) * 8);
#pragma unroll
      for (int j = 0; j < 8; j++)
        vf[j] = *(const short8*)(&Vs[cur][((kk * 4 + lg) * 128 + j * 16 + lq) * 8]);
#pragma unroll
      for (int i = 0; i < 2; i++)
#pragma unroll
        for (int j = 0; j < 8; j++)
          o[i][j] = __builtin_amdgcn_mfma_f32_16x16x32_bf16(pf[i], vf[j], o[i][j], 0, 0, 0);
    }
  }

  // epilogue: normalize, pack via wave-private P rows, write gemm2 A-pack tiles
#pragma unroll
  for (int i = 0; i < 2; i++) {
    float inv[4];
#pragma unroll
    for (int r = 0; r < 4; r++) inv[r] = 1.0f / lsum[i][r];
#pragma unroll
    for (int r = 0; r < 4; r++) {
      int prow = wOff + i * 16 + lg * 4 + r;
#pragma unroll
      for (int j = 0; j < 8; j++)
        Ps[((j * 2 + (lq >> 3)) * 128 + prow) * 8 + (lq & 7)] = f2bf(o[i][j][r] * inv[r]);
    }
  }
#pragma unroll
  for (int it = 0; it < 8; it++) {
    int row_loc = it * 4 + (lane >> 4);
    int cc = lane & 15;
    short8 v = *(const short8*)(Ps + (cc * 128 + wOff + row_loc) * 8);
    long tb = ((long)qt * 64 + h * 2 + (cc >> 3)) * 8192;
    *(short8*)(aop + tb + ((cc & 7) * 128 + wOff + row_loc) * 8) = v;
  }
}

// -------------------- launcher --------------------
extern "C" void kernel_launch(void* const* d_in, const int* in_sizes, int n_in,
                              void* d_out, int out_size, void* d_ws, size_t ws_size,
                              hipStream_t stream) {
  (void)in_sizes; (void)n_in; (void)out_size;
  const float* hs = (const float*)d_in[0];
  // d_in[1] = attention_mask: deterministic causal, applied analytically
  const float* wp = (const float*)d_in[2];
  const float* wo = (const float*)d_in[3];
  float* out = (float*)d_out;
  char* ws = (char*)d_ws;

  unsigned short* Ap1 = (unsigned short*)(ws);                 // X pack    16 MiB  @0
  unsigned short* Bp1 = (unsigned short*)(ws + 16777216);      // Wp pack   96 MiB  @16M
  unsigned short* Bp2 = (unsigned short*)(ws + 117440512);     // Wo pack   32 MiB  @112M
  unsigned short* Qf  = (unsigned short*)(ws + 150994944);     // Q pack    16 MiB  @144M
  unsigned short* Kf  = (unsigned short*)(ws + 167772160);     // K pack    16 MiB  @160M
  unsigned short* Vf  = (unsigned short*)(ws + 184549376);     // V^T pack  16 MiB  @176M
  unsigned short* aop = (unsigned short*)(ws + 201326592);     // ao pack   16 MiB  @192M
  if (ws_size < 218103808) return;  // need ~208 MiB

  // Q rows of w_pack (rows < 4096) pre-scaled by (1/sqrt(128))*log2(e)
  pack_fp32<<<dim3(16, 64), 256, 0, stream>>>(hs, Ap1, HID, 0, 1.0f);
  pack_fp32<<<dim3(96, 64), 256, 0, stream>>>(wp, Bp1, HID, 4096, 0.12751744154f);
  pack_fp32<<<dim3(32, 64), 256, 0, stream>>>(wo, Bp2, HID, 0, 1.0f);

  // gemm1: M=2048 (16 tiles), N=12288 (48 npairs) -> 768 blocks, QKV epilogue
  gemm_db<1><<<768, 512, 0, stream>>>(Ap1, Bp1, nullptr, PROJN, Qf, Kf, Vf, HID >> 6);

  attn_kernel<<<512, 256, 0, stream>>>(Qf, Kf, Vf, aop);

  // gemm2: M=2048 (16 tiles), N=4096 (16 npairs) -> 256 blocks, fp32 epilogue
  gemm_db<0><<<256, 512, 0, stream>>>(aop, Bp2, out, HID, nullptr, nullptr, nullptr, HID >> 6);
}

// Round 4
// 785.598 us; speedup vs baseline: 1.1373x; 1.1373x over previous
//
#include <hip/hip_runtime.h>
#include <stdint.h>

typedef __attribute__((ext_vector_type(8))) short short8;
typedef __attribute__((ext_vector_type(4))) short short4v;
typedef __attribute__((ext_vector_type(4))) float floatx4;

#define SEQ    2048
#define HID    4096
#define NHEAD  32
#define HDIMV  128
#define PROJN  12288

__device__ __forceinline__ unsigned short f2bf(float f) {
  union { float f; unsigned u; } v; v.f = f;
  unsigned r = (v.u + 0x7fffu + ((v.u >> 16) & 1u)) >> 16;
  return (unsigned short)r;
}

// -------------------- async 16B global->LDS --------------------
__device__ __forceinline__ void g2l16(const void* g, void* l) {
  __builtin_amdgcn_global_load_lds(
      (const __attribute__((address_space(1))) void*)g,
      (__attribute__((address_space(3))) void*)l, 16, 0, 0);
}

// ---------- fused pack: fp32 [R x 4096] row-major -> bf16 tile images ----------
// All three inputs (hs 16 tiles, wp 96 tiles, wo 32 tiles) in one launch.
// Tile (rp, kt) = 128 rows x 64 k, chunk-major: elem (r,c) at
// tile*8192 + ((c>>3)*128 + r)*8 + (c&7).
// Phase 1: COALESCED row reads (lane i reads 16B at row-offset i*16B),
// convert to bf16 into XOR-swizzled LDS tile (chunk ^= r&7 -> both phases
// bank-conflict-free, 8B/16B aligned). Phase 2: identical packed image as
// the old pack_fp32, coalesced 16B writes. wp tiles rp<32 (rows<4096 = Q rows)
// get the folded softmax scale (1/sqrt(128))*log2(e).
__global__ __launch_bounds__(256) void pack_all(
    const float* __restrict__ hs, const float* __restrict__ wp,
    const float* __restrict__ wo,
    unsigned short* __restrict__ Ap1, unsigned short* __restrict__ Bp1,
    unsigned short* __restrict__ Bp2) {
  __shared__ __align__(16) unsigned short T[128 * 64];
  const int rp_g = blockIdx.x, kt = blockIdx.y, t = threadIdx.x;
  const float* src;
  unsigned short* dst;
  int rp;
  float sc;
  if (rp_g < 16) {
    src = hs; dst = Ap1; rp = rp_g; sc = 1.0f;
  } else if (rp_g < 112) {
    src = wp; dst = Bp1; rp = rp_g - 16;
    sc = (rp < 32) ? 0.12751744154f : 1.0f;   // Q rows of w_pack
  } else {
    src = wo; dst = Bp2; rp = rp_g - 112; sc = 1.0f;
  }
  const long tb = ((long)rp * 64 + kt) * 8192;

  // phase 1: coalesced read of the 128x64 fp32 tile (16 rows/pass x 8)
#pragma unroll
  for (int pass = 0; pass < 8; pass++) {
    int r = pass * 16 + (t >> 4);
    int c4 = (t & 15) * 4;                    // logical col of this float4
    float4 a = *(const float4*)(src + (long)(rp * 128 + r) * HID + kt * 64 + c4);
    int chunk = (c4 >> 3) ^ (r & 7);          // swizzled chunk
    short4v o;
    o[0] = (short)f2bf(a.x * sc); o[1] = (short)f2bf(a.y * sc);
    o[2] = (short)f2bf(a.z * sc); o[3] = (short)f2bf(a.w * sc);
    *(short4v*)(T + r * 64 + chunk * 8 + (c4 & 7)) = o;
  }
  __syncthreads();

  // phase 2: packed-image writes (identical bytes to the old pack_fp32)
#pragma unroll
  for (int j = 0; j < 4; j++) {
    int ch = t + j * 256;
    int r = ch & 127, cc = ch >> 7;
    short8 o = *(const short8*)(T + r * 64 + ((cc ^ (r & 7)) * 8));
    *(short8*)(dst + tb + ch * 8) = o;
  }
}

// -------------------- NT GEMM on packed tiles (generic, for gemm2) ----------
template<int OUT_F32>
__global__ __launch_bounds__(256, 5) void gemm_pk(
    const unsigned short* __restrict__ Ap,
    const unsigned short* __restrict__ Bp,
    void* __restrict__ C, int N, int K) {
  __shared__ __align__(16) unsigned short As[8192];
  __shared__ __align__(16) unsigned short Bs[8192];
  const int t = threadIdx.x;
  const int wave = t >> 6, lane = t & 63;
  const int bid = blockIdx.x;
  const int xcd = bid & 7;
  const int li = bid >> 3;
  const int mi = li & 15;
  const int ni = (li >> 4) * 8 + xcd;
  const int KT = K >> 6;
  const unsigned short* at = Ap + (long)mi * KT * 8192 + t * 8;
  const unsigned short* bt = Bp + (long)ni * KT * 8192 + t * 8;
  unsigned short* asl = As + wave * 512;
  unsigned short* bsl = Bs + wave * 512;

  const int mw = (wave >> 1) * 64;
  const int nw = (wave & 1) * 64;
  const int lq = lane & 15, lg = lane >> 4;

  floatx4 zero = {0.f, 0.f, 0.f, 0.f};
  floatx4 acc[4][4];
  for (int i = 0; i < 4; i++)
    for (int j = 0; j < 4; j++) acc[i][j] = zero;

  for (int kt = 0; kt < KT; kt++) {
    __syncthreads();
    const unsigned short* ak = at + (long)kt * 8192;
    const unsigned short* bk = bt + (long)kt * 8192;
#pragma unroll
    for (int j = 0; j < 4; j++) g2l16(ak + j * 2048, asl + j * 2048);
#pragma unroll
    for (int j = 0; j < 4; j++) g2l16(bk + j * 2048, bsl + j * 2048);
    __syncthreads();
#pragma unroll
    for (int kk = 0; kk < 2; kk++) {
      const int ch = (kk * 4 + lg) * 1024;
      short8 af[4], bfr[4];
#pragma unroll
      for (int i = 0; i < 4; i++)
        af[i] = *(const short8*)(As + ch + (mw + i * 16 + lq) * 8);
#pragma unroll
      for (int j = 0; j < 4; j++)
        bfr[j] = *(const short8*)(Bs + ch + (nw + j * 16 + lq) * 8);
#pragma unroll
      for (int i = 0; i < 4; i++)
#pragma unroll
        for (int j = 0; j < 4; j++)
          acc[i][j] = __builtin_amdgcn_mfma_f32_16x16x32_bf16(af[i], bfr[j], acc[i][j], 0, 0, 0);
    }
  }

  const int row0 = mi * 128 + mw + lg * 4;
  const int col0 = ni * 128 + nw + lq;
  if (OUT_F32) {
    float* Cf = (float*)C;
#pragma unroll
    for (int i = 0; i < 4; i++)
#pragma unroll
      for (int j = 0; j < 4; j++)
#pragma unroll
        for (int r = 0; r < 4; r++)
          Cf[(long)(row0 + i * 16 + r) * N + col0 + j * 16] = acc[i][j][r];
  } else {
    unsigned short* Cb = (unsigned short*)C;
#pragma unroll
    for (int i = 0; i < 4; i++)
#pragma unroll
      for (int j = 0; j < 4; j++)
#pragma unroll
        for (int r = 0; r < 4; r++)
          Cb[(long)(row0 + i * 16 + r) * N + col0 + j * 16] = f2bf(acc[i][j][r]);
  }
}

// ---------- gemm1 with fused QKV re-pack epilogue ----------
// Output tile (mi, ni) of proj = X @ Wp^T maps exactly onto one packed tile:
//   ni in [ 0,32): Q head ni,    Qf tile (h*16 + mi), chunk-major (r=s_loc, c=d)
//   ni in [32,64): K head ni-32, Kf tile, same layout
//   ni in [64,96): V head ni-64, Vf tile, TRANSPOSED (row=d, k=s_loc)
// Chunk-major addr for elem (row,c): ((c>>3)*128 + row)*8 + (c&7).
__global__ __launch_bounds__(256, 5) void gemm_qkv(
    const unsigned short* __restrict__ Ap,
    const unsigned short* __restrict__ Bp,
    unsigned short* __restrict__ Qf,
    unsigned short* __restrict__ Kf,
    unsigned short* __restrict__ Vf) {
  __shared__ __align__(16) unsigned short As[8192];
  __shared__ __align__(16) unsigned short Bs[8192];
  const int t = threadIdx.x;
  const int wave = t >> 6, lane = t & 63;
  const int bid = blockIdx.x;
  const int xcd = bid & 7;
  const int li = bid >> 3;
  const int mi = li & 15;
  const int ni = (li >> 4) * 8 + xcd;
  const int KT = HID >> 6;
  const unsigned short* at = Ap + (long)mi * KT * 8192 + t * 8;
  const unsigned short* bt = Bp + (long)ni * KT * 8192 + t * 8;
  unsigned short* asl = As + wave * 512;
  unsigned short* bsl = Bs + wave * 512;

  const int mw = (wave >> 1) * 64;
  const int nw = (wave & 1) * 64;
  const int lq = lane & 15, lg = lane >> 4;

  floatx4 zero = {0.f, 0.f, 0.f, 0.f};
  floatx4 acc[4][4];
  for (int i = 0; i < 4; i++)
    for (int j = 0; j < 4; j++) acc[i][j] = zero;

  for (int kt = 0; kt < KT; kt++) {
    __syncthreads();
    const unsigned short* ak = at + (long)kt * 8192;
    const unsigned short* bk = bt + (long)kt * 8192;
#pragma unroll
    for (int j = 0; j < 4; j++) g2l16(ak + j * 2048, asl + j * 2048);
#pragma unroll
    for (int j = 0; j < 4; j++) g2l16(bk + j * 2048, bsl + j * 2048);
    __syncthreads();
#pragma unroll
    for (int kk = 0; kk < 2; kk++) {
      const int ch = (kk * 4 + lg) * 1024;
      short8 af[4], bfr[4];
#pragma unroll
      for (int i = 0; i < 4; i++)
        af[i] = *(const short8*)(As + ch + (mw + i * 16 + lq) * 8);
#pragma unroll
      for (int j = 0; j < 4; j++)
        bfr[j] = *(const short8*)(Bs + ch + (nw + j * 16 + lq) * 8);
#pragma unroll
      for (int i = 0; i < 4; i++)
#pragma unroll
        for (int j = 0; j < 4; j++)
          acc[i][j] = __builtin_amdgcn_mfma_f32_16x16x32_bf16(af[i], bfr[j], acc[i][j], 0, 0, 0);
    }
  }

  const int sec = ni >> 5;        // 0=Q, 1=K, 2=V
  const int h = ni & 31;
  unsigned short* dst =
      (sec == 0 ? Qf : (sec == 1 ? Kf : Vf)) + ((long)(h * 16 + mi)) * 16384;
  if (sec < 2) {
#pragma unroll
    for (int i = 0; i < 4; i++)
#pragma unroll
      for (int j = 0; j < 4; j++)
#pragma unroll
        for (int r = 0; r < 4; r++) {
          int row = mw + i * 16 + lg * 4 + r;      // local seq row
          int c = nw + j * 16 + lq;                // local head dim
          dst[((c >> 3) * 128 + row) * 8 + (c & 7)] = f2bf(acc[i][j][r]);
        }
  } else {
#pragma unroll
    for (int i = 0; i < 4; i++)
#pragma unroll
      for (int j = 0; j < 4; j++)
#pragma unroll
        for (int r = 0; r < 4; r++) {
          int s = mw + i * 16 + lg * 4 + r;        // local seq row (becomes k)
          int d = nw + j * 16 + lq;                // head dim (becomes row)
          dst[((s >> 3) * 128 + d) * 8 + (s & 7)] = f2bf(acc[i][j][r]);
        }
  }
}

// stage one contiguous 32KB packed tile into LDS (wave-cooperative, coalesced)
__device__ __forceinline__ void stage_tile(const unsigned short* g, unsigned short* lds,
                                           int wave, int lane) {
  const unsigned short* gp = g + wave * 4096 + lane * 8;
  unsigned short* lp = lds + wave * 4096;
#pragma unroll
  for (int j = 0; j < 8; j++) g2l16(gp + j * 512, lp + j * 512);
}

// -------------------- causal flash attention --------------------
// 512 blocks heavy-first: h = bx&31, qt = 15-(bx>>5). 4 waves, 32 q-rows each.
// K/V double-buffered in LDS (one barrier per kv iter, prefetch overlaps compute).
// Q frags in regs; P round-trip via wave-private 32KB LDS. Q pre-scaled (log2 dom).
__global__ __launch_bounds__(256, 1) void attn_kernel(
    const unsigned short* __restrict__ Qf,
    const unsigned short* __restrict__ Kf,
    const unsigned short* __restrict__ Vf,
    unsigned short* __restrict__ aop) {
  __shared__ __align__(16) unsigned short Ks[2][16384];
  __shared__ __align__(16) unsigned short Vs[2][16384];
  __shared__ __align__(16) unsigned short Ps[16384];
  const int bx = blockIdx.x;
  const int h = bx & 31;
  const int qt = 15 - (bx >> 5);
  const int t = threadIdx.x, wave = t >> 6, lane = t & 63;
  const int lq = lane & 15, lg = lane >> 4;
  const int wOff = wave * 32;

  // Q fragments: coalesced global reads from packed image (Q pre-scaled)
  const unsigned short* qb = Qf + ((long)(h * 16 + qt)) * 16384;
  short8 qf[2][4];
#pragma unroll
  for (int i = 0; i < 2; i++)
#pragma unroll
    for (int kk = 0; kk < 4; kk++)
      qf[i][kk] = *(const short8*)(qb + ((kk * 4 + lg) * 128 + wOff + i * 16 + lq) * 8);

  float mraw[2][4], lsum[2][4];
  floatx4 zero = {0.f, 0.f, 0.f, 0.f};
  floatx4 o[2][8];
#pragma unroll
  for (int i = 0; i < 2; i++)
#pragma unroll
    for (int r = 0; r < 4; r++) { mraw[i][r] = -INFINITY; lsum[i][r] = 0.f; }
#pragma unroll
  for (int i = 0; i < 2; i++)
#pragma unroll
    for (int j = 0; j < 8; j++) o[i][j] = zero;

  const unsigned short* kb0 = Kf + ((long)h * 16) * 16384;
  const unsigned short* vb0 = Vf + ((long)h * 16) * 16384;
  stage_tile(kb0, Ks[0], wave, lane);
  stage_tile(vb0, Vs[0], wave, lane);

  for (int kv = 0; kv <= qt; kv++) {
    const int cur = kv & 1;
    const bool diag = (kv == qt);
    __syncthreads();  // cur buffers staged; prev-iter LDS reads done
    if (!diag) {
      stage_tile(kb0 + (long)(kv + 1) * 16384, Ks[1 - cur], wave, lane);
      stage_tile(vb0 + (long)(kv + 1) * 16384, Vs[1 - cur], wave, lane);
    }

    // S = Q K^T (already in log2 domain via pre-scaled Q)
    floatx4 s[2][8];
#pragma unroll
    for (int i = 0; i < 2; i++)
#pragma unroll
      for (int j = 0; j < 8; j++) s[i][j] = zero;
#pragma unroll
    for (int kk = 0; kk < 4; kk++) {
      short8 bfr[8];
#pragma unroll
      for (int j = 0; j < 8; j++)
        bfr[j] = *(const short8*)(&Ks[cur][((kk * 4 + lg) * 128 + j * 16 + lq) * 8]);
#pragma unroll
      for (int i = 0; i < 2; i++)
#pragma unroll
        for (int j = 0; j < 8; j++)
          s[i][j] = __builtin_amdgcn_mfma_f32_16x16x32_bf16(qf[i][kk], bfr[j], s[i][j], 0, 0, 0);
    }

    if (diag) {
#pragma unroll
      for (int i = 0; i < 2; i++)
#pragma unroll
        for (int r = 0; r < 4; r++) {
          int qrow = qt * 128 + wOff + i * 16 + lg * 4 + r;
#pragma unroll
          for (int j = 0; j < 8; j++)
            if (kv * 128 + j * 16 + lq > qrow) s[i][j][r] = -INFINITY;
        }
    }

    // online softmax (log2 domain; rows lane-local, reduce over 16 col-lanes)
    float alpha_[2][4];
#pragma unroll
    for (int i = 0; i < 2; i++) {
#pragma unroll
      for (int r = 0; r < 4; r++) {
        float mx = s[i][0][r];
#pragma unroll
        for (int j = 1; j < 8; j++) mx = fmaxf(mx, s[i][j][r]);
#pragma unroll
        for (int d = 1; d < 16; d <<= 1) mx = fmaxf(mx, __shfl_xor(mx, d, 64));
        float mnew = fmaxf(mraw[i][r], mx);
        float al = exp2f(mraw[i][r] - mnew);
        float ps = 0.f;
#pragma unroll
        for (int j = 0; j < 8; j++) {
          float p = exp2f(s[i][j][r] - mnew);
          s[i][j][r] = p;
          ps += p;
        }
#pragma unroll
        for (int d = 1; d < 16; d <<= 1) ps += __shfl_xor(ps, d, 64);
        lsum[i][r] = lsum[i][r] * al + ps;
        mraw[i][r] = mnew;
        alpha_[i][r] = al;
      }
    }
#pragma unroll
    for (int i = 0; i < 2; i++)
#pragma unroll
      for (int j = 0; j < 8; j++)
#pragma unroll
        for (int r = 0; r < 4; r++) o[i][j][r] *= alpha_[i][r];

    // P (C-layout regs) -> chunk-major LDS, wave-private rows, no barrier
#pragma unroll
    for (int i = 0; i < 2; i++)
#pragma unroll
      for (int r = 0; r < 4; r++) {
        int prow = wOff + i * 16 + lg * 4 + r;
#pragma unroll
        for (int j = 0; j < 8; j++)
          Ps[((j * 2 + (lq >> 3)) * 128 + prow) * 8 + (lq & 7)] = f2bf(s[i][j][r]);
      }

    // O += P V (A-frags from own P rows, B-frags from Vs tile in LDS)
#pragma unroll
    for (int kk = 0; kk < 4; kk++) {
      short8 pf[2], vf[8];
#pragma unroll
      for (int i = 0; i < 2; i++)
        pf[i] = *(const short8*)(Ps + ((kk * 4 + lg) * 128 + wOff + i * 16 + lq) * 8);
#pragma unroll
      for (int j = 0; j < 8; j++)
        vf[j] = *(const short8*)(&Vs[cur][((kk * 4 + lg) * 128 + j * 16 + lq) * 8]);
#pragma unroll
      for (int i = 0; i < 2; i++)
#pragma unroll
        for (int j = 0; j < 8; j++)
          o[i][j] = __builtin_amdgcn_mfma_f32_16x16x32_bf16(pf[i], vf[j], o[i][j], 0, 0, 0);
    }
  }

  // epilogue: normalize, pack via wave-private P rows, write gemm2 A-pack tiles
#pragma unroll
  for (int i = 0; i < 2; i++) {
    float inv[4];
#pragma unroll
    for (int r = 0; r < 4; r++) inv[r] = 1.0f / lsum[i][r];
#pragma unroll
    for (int r = 0; r < 4; r++) {
      int prow = wOff + i * 16 + lg * 4 + r;
#pragma unroll
      for (int j = 0; j < 8; j++)
        Ps[((j * 2 + (lq >> 3)) * 128 + prow) * 8 + (lq & 7)] = f2bf(o[i][j][r] * inv[r]);
    }
  }
#pragma unroll
  for (int it = 0; it < 8; it++) {
    int row_loc = it * 4 + (lane >> 4);
    int cc = lane & 15;
    short8 v = *(const short8*)(Ps + (cc * 128 + wOff + row_loc) * 8);
    long tb = ((long)qt * 64 + h * 2 + (cc >> 3)) * 8192;
    *(short8*)(aop + tb + ((cc & 7) * 128 + wOff + row_loc) * 8) = v;
  }
}

// -------------------- launcher --------------------
extern "C" void kernel_launch(void* const* d_in, const int* in_sizes, int n_in,
                              void* d_out, int out_size, void* d_ws, size_t ws_size,
                              hipStream_t stream) {
  (void)in_sizes; (void)n_in; (void)out_size;
  const float* hs = (const float*)d_in[0];
  // d_in[1] = attention_mask: deterministic causal, applied analytically
  const float* wp = (const float*)d_in[2];
  const float* wo = (const float*)d_in[3];
  float* out = (float*)d_out;
  char* ws = (char*)d_ws;

  unsigned short* Ap1 = (unsigned short*)(ws);                 // X pack    16 MiB  @0
  unsigned short* Bp1 = (unsigned short*)(ws + 16777216);      // Wp pack   96 MiB  @16M
  unsigned short* Bp2 = (unsigned short*)(ws + 117440512);     // Wo pack   32 MiB  @112M
  unsigned short* Qf  = (unsigned short*)(ws + 150994944);     // Q pack    16 MiB  @144M
  unsigned short* Kf  = (unsigned short*)(ws + 167772160);     // K pack    16 MiB  @160M
  unsigned short* Vf  = (unsigned short*)(ws + 184549376);     // V^T pack  16 MiB  @176M
  unsigned short* aop = (unsigned short*)(ws + 201326592);     // ao pack   16 MiB  @192M
  if (ws_size < 218103808) return;  // need ~208 MiB

  // fused pack: hs (tiles 0-15), wp (16-111, Q rows pre-scaled), wo (112-143)
  pack_all<<<dim3(144, 64), 256, 0, stream>>>(hs, wp, wo, Ap1, Bp1, Bp2);

  // gemm1: M=2048 (16 tiles), N=12288 (96 tiles) -> 1536 blocks, QKV epilogue
  gemm_qkv<<<1536, 256, 0, stream>>>(Ap1, Bp1, Qf, Kf, Vf);

  attn_kernel<<<512, 256, 0, stream>>>(Qf, Kf, Vf, aop);

  // gemm2: M=2048, N=4096 -> 512 blocks, fp32 epilogue
  gemm_pk<1><<<512, 256, 0, stream>>>(aop, Bp2, (void*)out, HID, HID);
}

// Round 5
// 779.513 us; speedup vs baseline: 1.1462x; 1.0078x over previous
//
#include <hip/hip_runtime.h>
#include <stdint.h>

typedef __attribute__((ext_vector_type(8))) short short8;
typedef __attribute__((ext_vector_type(4))) short short4v;
typedef __attribute__((ext_vector_type(4))) float floatx4;

#define SEQ    2048
#define HID    4096
#define NHEAD  32
#define HDIMV  128
#define PROJN  12288

__device__ __forceinline__ unsigned short f2bf(float f) {
  union { float f; unsigned u; } v; v.f = f;
  unsigned r = (v.u + 0x7fffu + ((v.u >> 16) & 1u)) >> 16;
  return (unsigned short)r;
}

// -------------------- async 16B global->LDS --------------------
__device__ __forceinline__ void g2l16(const void* g, void* l) {
  __builtin_amdgcn_global_load_lds(
      (const __attribute__((address_space(1))) void*)g,
      (__attribute__((address_space(3))) void*)l, 16, 0, 0);
}

// ---------- fused pack: fp32 [R x 4096] row-major -> bf16 tile images ----------
// All three inputs (hs 16 tiles, wp 96 tiles, wo 32 tiles) in one launch.
// Tile (rp, kt) = 128 rows x 64 k, chunk-major: elem (r,c) at
// tile*8192 + ((c>>3)*128 + r)*8 + (c&7).
__global__ __launch_bounds__(256) void pack_all(
    const float* __restrict__ hs, const float* __restrict__ wp,
    const float* __restrict__ wo,
    unsigned short* __restrict__ Ap1, unsigned short* __restrict__ Bp1,
    unsigned short* __restrict__ Bp2) {
  __shared__ __align__(16) unsigned short T[128 * 64];
  const int rp_g = blockIdx.x, kt = blockIdx.y, t = threadIdx.x;
  const float* src;
  unsigned short* dst;
  int rp;
  float sc;
  if (rp_g < 16) {
    src = hs; dst = Ap1; rp = rp_g; sc = 1.0f;
  } else if (rp_g < 112) {
    src = wp; dst = Bp1; rp = rp_g - 16;
    sc = (rp < 32) ? 0.12751744154f : 1.0f;   // Q rows of w_pack
  } else {
    src = wo; dst = Bp2; rp = rp_g - 112; sc = 1.0f;
  }
  const long tb = ((long)rp * 64 + kt) * 8192;

  // phase 1: coalesced read of the 128x64 fp32 tile (16 rows/pass x 8)
#pragma unroll
  for (int pass = 0; pass < 8; pass++) {
    int r = pass * 16 + (t >> 4);
    int c4 = (t & 15) * 4;                    // logical col of this float4
    float4 a = *(const float4*)(src + (long)(rp * 128 + r) * HID + kt * 64 + c4);
    int chunk = (c4 >> 3) ^ (r & 7);          // swizzled chunk
    short4v o;
    o[0] = (short)f2bf(a.x * sc); o[1] = (short)f2bf(a.y * sc);
    o[2] = (short)f2bf(a.z * sc); o[3] = (short)f2bf(a.w * sc);
    *(short4v*)(T + r * 64 + chunk * 8 + (c4 & 7)) = o;
  }
  __syncthreads();

  // phase 2: packed-image writes (identical bytes to the old pack_fp32)
#pragma unroll
  for (int j = 0; j < 4; j++) {
    int ch = t + j * 256;
    int r = ch & 127, cc = ch >> 7;
    short8 o = *(const short8*)(T + r * 64 + ((cc ^ (r & 7)) * 8));
    *(short8*)(dst + tb + ch * 8) = o;
  }
}

// -------------------- NT GEMM on packed tiles (generic, for gemm2) ----------
template<int OUT_F32>
__global__ __launch_bounds__(256, 5) void gemm_pk(
    const unsigned short* __restrict__ Ap,
    const unsigned short* __restrict__ Bp,
    void* __restrict__ C, int N, int K) {
  __shared__ __align__(16) unsigned short As[8192];
  __shared__ __align__(16) unsigned short Bs[8192];
  const int t = threadIdx.x;
  const int wave = t >> 6, lane = t & 63;
  const int bid = blockIdx.x;
  const int xcd = bid & 7;
  const int li = bid >> 3;
  const int mi = li & 15;
  const int ni = (li >> 4) * 8 + xcd;
  const int KT = K >> 6;
  const unsigned short* at = Ap + (long)mi * KT * 8192 + t * 8;
  const unsigned short* bt = Bp + (long)ni * KT * 8192 + t * 8;
  unsigned short* asl = As + wave * 512;
  unsigned short* bsl = Bs + wave * 512;

  const int mw = (wave >> 1) * 64;
  const int nw = (wave & 1) * 64;
  const int lq = lane & 15, lg = lane >> 4;

  floatx4 zero = {0.f, 0.f, 0.f, 0.f};
  floatx4 acc[4][4];
  for (int i = 0; i < 4; i++)
    for (int j = 0; j < 4; j++) acc[i][j] = zero;

  for (int kt = 0; kt < KT; kt++) {
    __syncthreads();
    const unsigned short* ak = at + (long)kt * 8192;
    const unsigned short* bk = bt + (long)kt * 8192;
#pragma unroll
    for (int j = 0; j < 4; j++) g2l16(ak + j * 2048, asl + j * 2048);
#pragma unroll
    for (int j = 0; j < 4; j++) g2l16(bk + j * 2048, bsl + j * 2048);
    __syncthreads();
#pragma unroll
    for (int kk = 0; kk < 2; kk++) {
      const int ch = (kk * 4 + lg) * 1024;
      short8 af[4], bfr[4];
#pragma unroll
      for (int i = 0; i < 4; i++)
        af[i] = *(const short8*)(As + ch + (mw + i * 16 + lq) * 8);
#pragma unroll
      for (int j = 0; j < 4; j++)
        bfr[j] = *(const short8*)(Bs + ch + (nw + j * 16 + lq) * 8);
#pragma unroll
      for (int i = 0; i < 4; i++)
#pragma unroll
        for (int j = 0; j < 4; j++)
          acc[i][j] = __builtin_amdgcn_mfma_f32_16x16x32_bf16(af[i], bfr[j], acc[i][j], 0, 0, 0);
    }
  }

  const int row0 = mi * 128 + mw + lg * 4;
  const int col0 = ni * 128 + nw + lq;
  if (OUT_F32) {
    float* Cf = (float*)C;
#pragma unroll
    for (int i = 0; i < 4; i++)
#pragma unroll
      for (int j = 0; j < 4; j++)
#pragma unroll
        for (int r = 0; r < 4; r++)
          Cf[(long)(row0 + i * 16 + r) * N + col0 + j * 16] = acc[i][j][r];
  } else {
    unsigned short* Cb = (unsigned short*)C;
#pragma unroll
    for (int i = 0; i < 4; i++)
#pragma unroll
      for (int j = 0; j < 4; j++)
#pragma unroll
        for (int r = 0; r < 4; r++)
          Cb[(long)(row0 + i * 16 + r) * N + col0 + j * 16] = f2bf(acc[i][j][r]);
  }
}

// ---------- gemm1 with fused QKV re-pack epilogue ----------
__global__ __launch_bounds__(256, 5) void gemm_qkv(
    const unsigned short* __restrict__ Ap,
    const unsigned short* __restrict__ Bp,
    unsigned short* __restrict__ Qf,
    unsigned short* __restrict__ Kf,
    unsigned short* __restrict__ Vf) {
  __shared__ __align__(16) unsigned short As[8192];
  __shared__ __align__(16) unsigned short Bs[8192];
  const int t = threadIdx.x;
  const int wave = t >> 6, lane = t & 63;
  const int bid = blockIdx.x;
  const int xcd = bid & 7;
  const int li = bid >> 3;
  const int mi = li & 15;
  const int ni = (li >> 4) * 8 + xcd;
  const int KT = HID >> 6;
  const unsigned short* at = Ap + (long)mi * KT * 8192 + t * 8;
  const unsigned short* bt = Bp + (long)ni * KT * 8192 + t * 8;
  unsigned short* asl = As + wave * 512;
  unsigned short* bsl = Bs + wave * 512;

  const int mw = (wave >> 1) * 64;
  const int nw = (wave & 1) * 64;
  const int lq = lane & 15, lg = lane >> 4;

  floatx4 zero = {0.f, 0.f, 0.f, 0.f};
  floatx4 acc[4][4];
  for (int i = 0; i < 4; i++)
    for (int j = 0; j < 4; j++) acc[i][j] = zero;

  for (int kt = 0; kt < KT; kt++) {
    __syncthreads();
    const unsigned short* ak = at + (long)kt * 8192;
    const unsigned short* bk = bt + (long)kt * 8192;
#pragma unroll
    for (int j = 0; j < 4; j++) g2l16(ak + j * 2048, asl + j * 2048);
#pragma unroll
    for (int j = 0; j < 4; j++) g2l16(bk + j * 2048, bsl + j * 2048);
    __syncthreads();
#pragma unroll
    for (int kk = 0; kk < 2; kk++) {
      const int ch = (kk * 4 + lg) * 1024;
      short8 af[4], bfr[4];
#pragma unroll
      for (int i = 0; i < 4; i++)
        af[i] = *(const short8*)(As + ch + (mw + i * 16 + lq) * 8);
#pragma unroll
      for (int j = 0; j < 4; j++)
        bfr[j] = *(const short8*)(Bs + ch + (nw + j * 16 + lq) * 8);
#pragma unroll
      for (int i = 0; i < 4; i++)
#pragma unroll
        for (int j = 0; j < 4; j++)
          acc[i][j] = __builtin_amdgcn_mfma_f32_16x16x32_bf16(af[i], bfr[j], acc[i][j], 0, 0, 0);
    }
  }

  const int sec = ni >> 5;        // 0=Q, 1=K, 2=V
  const int h = ni & 31;
  unsigned short* dst =
      (sec == 0 ? Qf : (sec == 1 ? Kf : Vf)) + ((long)(h * 16 + mi)) * 16384;
  if (sec < 2) {
#pragma unroll
    for (int i = 0; i < 4; i++)
#pragma unroll
      for (int j = 0; j < 4; j++)
#pragma unroll
        for (int r = 0; r < 4; r++) {
          int row = mw + i * 16 + lg * 4 + r;      // local seq row
          int c = nw + j * 16 + lq;                // local head dim
          dst[((c >> 3) * 128 + row) * 8 + (c & 7)] = f2bf(acc[i][j][r]);
        }
  } else {
#pragma unroll
    for (int i = 0; i < 4; i++)
#pragma unroll
      for (int j = 0; j < 4; j++)
#pragma unroll
        for (int r = 0; r < 4; r++) {
          int s = mw + i * 16 + lg * 4 + r;        // local seq row (becomes k)
          int d = nw + j * 16 + lq;                // head dim (becomes row)
          dst[((s >> 3) * 128 + d) * 8 + (s & 7)] = f2bf(acc[i][j][r]);
        }
  }
}

// -------------------- causal flash attention, KVBLK=64 --------------------
// 512 blocks, balanced pairing: h = bx&31, idx = bx>>5,
// qt = idx<8 ? 15-idx : idx-8 (co-resident pairs sum to constant work).
// LDS: Ks 2x16KB (64kv x 128d, 64-row chunk-major) + Vs 2x16KB (contiguous
// halves of packed V^T) + Ps 16KB = 80KB -> 2 blocks/CU, all 512 co-resident.
// Double-buffered kv tiles, one barrier per iter; epilogue reuses Ks as 32KB
// scratch after a final barrier. T5 setprio around MFMA clusters (2 blk/CU ->
// real wave arbitration). Q pre-scaled (log2 domain).
__global__ __launch_bounds__(256, 2) void attn_kernel(
    const unsigned short* __restrict__ Qf,
    const unsigned short* __restrict__ Kf,
    const unsigned short* __restrict__ Vf,
    unsigned short* __restrict__ aop) {
  __shared__ __align__(16) unsigned short Ks[2][8192];
  __shared__ __align__(16) unsigned short Vs[2][8192];
  __shared__ __align__(16) unsigned short Ps[8192];
  const int bx = blockIdx.x;
  const int h = bx & 31;
  const int idx = bx >> 5;
  const int qt = (idx < 8) ? (15 - idx) : (idx - 8);
  const int t = threadIdx.x, wave = t >> 6, lane = t & 63;
  const int lq = lane & 15, lg = lane >> 4;
  const int wOff = wave * 32;

  // Q fragments: coalesced global reads from packed image (Q pre-scaled)
  const unsigned short* qb = Qf + ((long)(h * 16 + qt)) * 16384;
  short8 qf[2][4];
#pragma unroll
  for (int i = 0; i < 2; i++)
#pragma unroll
    for (int kk = 0; kk < 4; kk++)
      qf[i][kk] = *(const short8*)(qb + ((kk * 4 + lg) * 128 + wOff + i * 16 + lq) * 8);

  float mraw[2][4], lsum[2][4];
  floatx4 zero = {0.f, 0.f, 0.f, 0.f};
  floatx4 o[2][8];
#pragma unroll
  for (int i = 0; i < 2; i++)
#pragma unroll
    for (int r = 0; r < 4; r++) { mraw[i][r] = -INFINITY; lsum[i][r] = 0.f; }
#pragma unroll
  for (int i = 0; i < 2; i++)
#pragma unroll
    for (int j = 0; j < 8; j++) o[i][j] = zero;

  const unsigned short* kb0 = Kf + ((long)h * 16) * 16384;
  const unsigned short* vb0 = Vf + ((long)h * 16) * 16384;
  const int nkv = 2 * qt + 2;   // 64-wide kv tiles

  // K half-tile (kvt): rows (kvt&1)*64..+64 of 128-row packed tile (kvt>>1).
  // 16 chunks x 512 shorts, strided 1024 in global; linear in LDS.
  auto stageK = [&](int buf, int kvt) {
    const unsigned short* g = kb0 + (long)(kvt >> 1) * 16384 + (kvt & 1) * 512;
#pragma unroll
    for (int j = 0; j < 4; j++) {
      int run = wave * 4 + j;
      g2l16(g + run * 1024 + lane * 8, &Ks[buf][run * 512 + lane * 8]);
    }
  };
  // V^T half-tile (kvt): kv cols (kvt&1)*64..+64 = contiguous 8192 shorts.
  auto stageV = [&](int buf, int kvt) {
    const unsigned short* g = vb0 + (long)(kvt >> 1) * 16384 + (kvt & 1) * 8192;
#pragma unroll
    for (int j = 0; j < 4; j++) {
      int run = wave * 4 + j;
      g2l16(g + run * 512 + lane * 8, &Vs[buf][run * 512 + lane * 8]);
    }
  };

  stageK(0, 0);
  stageV(0, 0);

  for (int kvt = 0; kvt < nkv; kvt++) {
    const int cur = kvt & 1;
    __syncthreads();  // cur buffers staged; prev-iter LDS reads done
    if (kvt + 1 < nkv) {
      stageK(1 - cur, kvt + 1);
      stageV(1 - cur, kvt + 1);
    }

    // S = Q K^T (log2 domain), 32x64 per wave
    floatx4 s[2][4];
#pragma unroll
    for (int i = 0; i < 2; i++)
#pragma unroll
      for (int j = 0; j < 4; j++) s[i][j] = zero;
#pragma unroll
    for (int kk = 0; kk < 4; kk++) {
      short8 bfr[4];
#pragma unroll
      for (int j = 0; j < 4; j++)
        bfr[j] = *(const short8*)(&Ks[cur][((kk * 4 + lg) * 64 + j * 16 + lq) * 8]);
      __builtin_amdgcn_s_setprio(1);
#pragma unroll
      for (int i = 0; i < 2; i++)
#pragma unroll
        for (int j = 0; j < 4; j++)
          s[i][j] = __builtin_amdgcn_mfma_f32_16x16x32_bf16(qf[i][kk], bfr[j], s[i][j], 0, 0, 0);
      __builtin_amdgcn_s_setprio(0);
    }

    if (kvt >= 2 * qt) {  // last two tiles touch the diagonal
#pragma unroll
      for (int i = 0; i < 2; i++)
#pragma unroll
        for (int r = 0; r < 4; r++) {
          int qrow = qt * 128 + wOff + i * 16 + lg * 4 + r;
#pragma unroll
          for (int j = 0; j < 4; j++)
            if (kvt * 64 + j * 16 + lq > qrow) s[i][j][r] = -INFINITY;
        }
    }

    // online softmax (log2 domain; rows lane-local, reduce over 16 col-lanes)
    float alpha_[2][4];
#pragma unroll
    for (int i = 0; i < 2; i++) {
#pragma unroll
      for (int r = 0; r < 4; r++) {
        float mx = s[i][0][r];
#pragma unroll
        for (int j = 1; j < 4; j++) mx = fmaxf(mx, s[i][j][r]);
#pragma unroll
        for (int d = 1; d < 16; d <<= 1) mx = fmaxf(mx, __shfl_xor(mx, d, 64));
        float mnew = fmaxf(mraw[i][r], mx);
        float al = exp2f(mraw[i][r] - mnew);
        float ps = 0.f;
#pragma unroll
        for (int j = 0; j < 4; j++) {
          float p = exp2f(s[i][j][r] - mnew);
          s[i][j][r] = p;
          ps += p;
        }
#pragma unroll
        for (int d = 1; d < 16; d <<= 1) ps += __shfl_xor(ps, d, 64);
        lsum[i][r] = lsum[i][r] * al + ps;
        mraw[i][r] = mnew;
        alpha_[i][r] = al;
      }
    }
#pragma unroll
    for (int i = 0; i < 2; i++)
#pragma unroll
      for (int j = 0; j < 8; j++)
#pragma unroll
        for (int r = 0; r < 4; r++) o[i][j][r] *= alpha_[i][r];

    // P (C-layout regs) -> chunk-major LDS, wave-private rows, no barrier
#pragma unroll
    for (int i = 0; i < 2; i++)
#pragma unroll
      for (int r = 0; r < 4; r++) {
        int prow = wOff + i * 16 + lg * 4 + r;
#pragma unroll
        for (int j = 0; j < 4; j++)
          Ps[((j * 2 + (lq >> 3)) * 128 + prow) * 8 + (lq & 7)] = f2bf(s[i][j][r]);
      }

    // O += P V (A-frags from own P rows, B-frags from Vs half-tile)
#pragma unroll
    for (int kk = 0; kk < 2; kk++) {
      short8 pf[2], vf[8];
#pragma unroll
      for (int i = 0; i < 2; i++)
        pf[i] = *(const short8*)(Ps + ((kk * 4 + lg) * 128 + wOff + i * 16 + lq) * 8);
#pragma unroll
      for (int j = 0; j < 8; j++)
        vf[j] = *(const short8*)(&Vs[cur][((kk * 4 + lg) * 128 + j * 16 + lq) * 8]);
      __builtin_amdgcn_s_setprio(1);
#pragma unroll
      for (int i = 0; i < 2; i++)
#pragma unroll
        for (int j = 0; j < 8; j++)
          o[i][j] = __builtin_amdgcn_mfma_f32_16x16x32_bf16(pf[i], vf[j], o[i][j], 0, 0, 0);
      __builtin_amdgcn_s_setprio(0);
    }
  }

  // epilogue: normalize, pack via 32KB scratch (Ks reused; all reads done)
  __syncthreads();
  unsigned short* Es = &Ks[0][0];  // 16384 shorts = 32KB, wave-private rows
#pragma unroll
  for (int i = 0; i < 2; i++) {
    float inv[4];
#pragma unroll
    for (int r = 0; r < 4; r++) inv[r] = 1.0f / lsum[i][r];
#pragma unroll
    for (int r = 0; r < 4; r++) {
      int prow = wOff + i * 16 + lg * 4 + r;
#pragma unroll
      for (int j = 0; j < 8; j++)
        Es[((j * 2 + (lq >> 3)) * 128 + prow) * 8 + (lq & 7)] = f2bf(o[i][j][r] * inv[r]);
    }
  }
#pragma unroll
  for (int it = 0; it < 8; it++) {
    int row_loc = it * 4 + (lane >> 4);
    int cc = lane & 15;
    short8 v = *(const short8*)(Es + (cc * 128 + wOff + row_loc) * 8);
    long tb = ((long)qt * 64 + h * 2 + (cc >> 3)) * 8192;
    *(short8*)(aop + tb + ((cc & 7) * 128 + wOff + row_loc) * 8) = v;
  }
}

// -------------------- launcher --------------------
extern "C" void kernel_launch(void* const* d_in, const int* in_sizes, int n_in,
                              void* d_out, int out_size, void* d_ws, size_t ws_size,
                              hipStream_t stream) {
  (void)in_sizes; (void)n_in; (void)out_size;
  const float* hs = (const float*)d_in[0];
  // d_in[1] = attention_mask: deterministic causal, applied analytically
  const float* wp = (const float*)d_in[2];
  const float* wo = (const float*)d_in[3];
  float* out = (float*)d_out;
  char* ws = (char*)d_ws;

  unsigned short* Ap1 = (unsigned short*)(ws);                 // X pack    16 MiB  @0
  unsigned short* Bp1 = (unsigned short*)(ws + 16777216);      // Wp pack   96 MiB  @16M
  unsigned short* Bp2 = (unsigned short*)(ws + 117440512);     // Wo pack   32 MiB  @112M
  unsigned short* Qf  = (unsigned short*)(ws + 150994944);     // Q pack    16 MiB  @144M
  unsigned short* Kf  = (unsigned short*)(ws + 167772160);     // K pack    16 MiB  @160M
  unsigned short* Vf  = (unsigned short*)(ws + 184549376);     // V^T pack  16 MiB  @176M
  unsigned short* aop = (unsigned short*)(ws + 201326592);     // ao pack   16 MiB  @192M
  if (ws_size < 218103808) return;  // need ~208 MiB

  // fused pack: hs (tiles 0-15), wp (16-111, Q rows pre-scaled), wo (112-143)
  pack_all<<<dim3(144, 64), 256, 0, stream>>>(hs, wp, wo, Ap1, Bp1, Bp2);

  // gemm1: M=2048 (16 tiles), N=12288 (96 tiles) -> 1536 blocks, QKV epilogue
  gemm_qkv<<<1536, 256, 0, stream>>>(Ap1, Bp1, Qf, Kf, Vf);

  attn_kernel<<<512, 256, 0, stream>>>(Qf, Kf, Vf, aop);

  // gemm2: M=2048, N=4096 -> 512 blocks, fp32 epilogue
  gemm_pk<1><<<512, 256, 0, stream>>>(aop, Bp2, (void*)out, HID, HID);
}